// Round 12
// baseline (118.324 us; speedup 1.0000x reference)
//
#include <hip/hip_runtime.h>

// Problem constants (match reference)
#define N_PTS 32768
#define E_EDGES 524288
#define THREADS 256
#define NB_HEAVY 8192            // 32-col blocks: exactly 4.0 rounds at 2048 residency
#define NB_LIGHT 1024            // 16-col blocks (supertile 0 off-diag), half-duration tail
#define NB 9216
#define EPB 57                   // attract edges per block (57*9216 >= E)
#define NSLOTS 64                // spread accumulator slots

typedef float f32x2 __attribute__((ext_vector_type(2)));

// Packed f32 VOP3P ops (issue-slot compression; f32 throughput unchanged)
#define PK_SUB(d, a, b) \
    asm("v_pk_add_f32 %0, %1, %2 neg_lo:[0,1] neg_hi:[0,1]" : "=v"(d) : "v"(a), "v"(b))
#define PK_FMA(d, a, b, c) \
    asm("v_pk_fma_f32 %0, %1, %2, %3" : "=v"(d) : "v"(a), "v"(b), "v"(c))
#define PK_MUL_IP(d, a) \
    asm("v_pk_mul_f32 %0, %0, %1" : "+v"(d) : "v"(a))

// ws layout: ws[0..63] = acc_r slots, ws[64..127] = acc_a slots (doubles)

// Fused kernel. Repulsive (L_ij = L_ji): supertile I = rows [2048I, 2048(I+1)).
// Each block: one supertile, one contiguous col range (32 or 16 cols), never
// crossing a supertile boundary. Diagonal region (first 2048 cols): row-side
// only, full square. Off-diag: dual row+col accumulation covers (i,j)+(j,i).
// Per pair: b = 1+dx^2+dy^2 (>=1 in fp, no clamp); a = fma(b,1+eps,-1).
__global__ __launch_bounds__(256) void fused_kernel(
    const float* __restrict__ emb,
    const float* __restrict__ deg,
    const float* __restrict__ sparse,
    const int* __restrict__ heads,
    const int* __restrict__ tails,
    double* __restrict__ acc) {
    const int b = blockIdx.x;
    const int tid = threadIdx.x;

    // ---- attract prefetch: issue index/weight loads now, compute later ----
    int eh_i = 0, et_i = 0;
    float sp = 0.0f;
    const int e = b * EPB + tid;
    const bool doE = (tid < EPB) && (e < E_EDGES);
    if (doE) { eh_i = heads[e]; et_i = tails[e]; sp = sparse[e]; }

    // ---- map blockIdx -> (supertile I, col0, ngroups, diag) ----
    int I, col0, ngroups;
    bool diag;
    if (b >= NB_HEAVY) {            // light tail: supertile 0, cols [16384,32768)
        I = 0; col0 = 16384 + ((b - NB_HEAVY) << 4); ngroups = 2; diag = false;
    } else if (b < 512) {           // supertile 0 heavy: cols [0,16384)
        I = 0; col0 = b << 5; ngroups = 4; diag = (b < 64);
    } else {                        // supertiles 1..15, 1024-64*I blocks each
        int w = b - 512; I = 1; int cnt = 960;
        while (w >= cnt) { w -= cnt; ++I; cnt -= 64; }
        col0 = (I << 11) + (w << 5); ngroups = 4; diag = (w < 64);
    }

    const f32x2 ONE2 = {1.0f, 1.0f};
    const f32x2 EPS2 = {1.0001f, 1.0001f};
    const f32x2 M1_2 = {-1.0f, -1.0f};

    // rows of supertile I (8 per thread, 4 packed pairs)
    const int ibase = (I << 11) + tid;
    f32x2 rx[4], ry[4];
    #pragma unroll
    for (int p = 0; p < 4; ++p) {
        float2 pA = *reinterpret_cast<const float2*>(emb + 2 * (ibase + (2 * p + 0) * THREADS));
        float2 pB = *reinterpret_cast<const float2*>(emb + 2 * (ibase + (2 * p + 1) * THREADS));
        rx[p] = (f32x2){pA.x, pB.x};
        ry[p] = (f32x2){pA.y, pB.y};
    }

    float S[8];
    #pragma unroll
    for (int r = 0; r < 8; ++r) S[r] = 0.0f;
    float colAcc0 = 0.0f, colAcc1 = 0.0f;   // dual accumulators: break fma chain

#define CORE(p, FJ, CM)                                           \
    {                                                             \
        f32x2 dx_, dy_, t_, b_, a_;                               \
        PK_SUB(dx_, rx[p], Jx);                                   \
        PK_SUB(dy_, ry[p], Jy);                                   \
        PK_FMA(t_, dy_, dy_, ONE2);                               \
        PK_FMA(b_, dx_, dx_, t_);                                 \
        PK_FMA(a_, b_, EPS2, M1_2);                               \
        if (FJ) { pa[p] = a_; pb[p] = b_; }                       \
        else    { PK_MUL_IP(pa[p], a_); PK_MUL_IP(pb[p], b_); }   \
        if (CM == 1) { pc_a = a_; pc_b = b_; }                    \
        if (CM == 2) { PK_MUL_IP(pc_a, a_); PK_MUL_IP(pc_b, b_); }\
    }

#define OFFJ(FJ, xj, yj, dval, CACC)                              \
    {                                                             \
        f32x2 Jx = {(xj), (xj)}, Jy = {(yj), (yj)};               \
        f32x2 pc_a, pc_b;                                         \
        CORE(0, FJ, 1) CORE(1, FJ, 2) CORE(2, FJ, 2) CORE(3, FJ, 2) \
        float qa_ = pc_a.x * pc_a.y;                              \
        float qb_ = pc_b.x * pc_b.y;                              \
        CACC = fmaf((dval), __log2f(qa_) - __log2f(qb_), CACC);   \
    }

#define DIAJ(FJ, xj, yj)                                          \
    {                                                             \
        f32x2 Jx = {(xj), (xj)}, Jy = {(yj), (yj)};               \
        f32x2 pc_a, pc_b; (void)pc_a; (void)pc_b;                 \
        CORE(0, FJ, 0) CORE(1, FJ, 0) CORE(2, FJ, 0) CORE(3, FJ, 0) \
    }

#define ROWFLUSH                                                  \
    _Pragma("unroll")                                             \
    for (int p = 0; p < 4; ++p) {                                 \
        S[2 * p + 0] += __log2f(pa[p].x) - __log2f(pb[p].x);      \
        S[2 * p + 1] += __log2f(pa[p].y) - __log2f(pb[p].y);      \
    }

    const float4* __restrict__ P4 = reinterpret_cast<const float4*>(emb) + (col0 >> 1);
    if (!diag) {
        for (int g = 0; g < ngroups; ++g) {
            const float4* P4b = P4 + (g << 2);
            float4 A = P4b[0], B = P4b[1], C = P4b[2], D = P4b[3];
            const float4* dj = reinterpret_cast<const float4*>(deg + col0) + (g << 1);
            float4 dj0 = dj[0], dj1 = dj[1];
            f32x2 pa[4], pb[4];
            OFFJ(1, A.x, A.y, dj0.x, colAcc0) OFFJ(0, A.z, A.w, dj0.y, colAcc1)
            OFFJ(0, B.x, B.y, dj0.z, colAcc0) OFFJ(0, B.z, B.w, dj0.w, colAcc1)
            OFFJ(0, C.x, C.y, dj1.x, colAcc0) OFFJ(0, C.z, C.w, dj1.y, colAcc1)
            OFFJ(0, D.x, D.y, dj1.z, colAcc0) OFFJ(0, D.z, D.w, dj1.w, colAcc1)
            ROWFLUSH
        }
    } else {
        for (int g = 0; g < ngroups; ++g) {
            const float4* P4b = P4 + (g << 2);
            float4 A = P4b[0], B = P4b[1], C = P4b[2], D = P4b[3];
            f32x2 pa[4], pb[4];
            DIAJ(1, A.x, A.y) DIAJ(0, A.z, A.w)
            DIAJ(0, B.x, B.y) DIAJ(0, B.z, B.w)
            DIAJ(0, C.x, C.y) DIAJ(0, C.z, C.w)
            DIAJ(0, D.x, D.y) DIAJ(0, D.z, D.w)
            ROWFLUSH
        }
    }
#undef CORE
#undef OFFJ
#undef DIAJ
#undef ROWFLUSH

    // row flush: weight by d_i (two independent fma chains)
    float c0 = colAcc0, c1 = colAcc1;
    #pragma unroll
    for (int p = 0; p < 4; ++p) {
        c0 = fmaf(deg[ibase + (2 * p + 0) * THREADS], S[2 * p + 0], c0);
        c1 = fmaf(deg[ibase + (2 * p + 1) * THREADS], S[2 * p + 1], c1);
    }
    float contrib = c0 + c1;

    // ---- attract epilogue: gathers + log (indices prefetched at top) ----
    float aLocal = 0.0f;
    if (doE) {
        float2 eh = *reinterpret_cast<const float2*>(emb + 2 * eh_i);
        float2 et = *reinterpret_cast<const float2*>(emb + 2 * et_i);
        float dx = eh.x - et.x;
        float dy = eh.y - et.y;
        float sqd = fmaf(dx, dx, dy * dy);
        aLocal = sp * __log2f(1.0f + sqd);
    }

    for (int off = 32; off; off >>= 1) {
        contrib += __shfl_down(contrib, off, 64);
        aLocal  += __shfl_down(aLocal,  off, 64);
    }
    if ((tid & 63) == 0) {
        int slot = b & (NSLOTS - 1);
        atomicAdd(&acc[slot], (double)contrib);
        atomicAdd(&acc[NSLOTS + slot], (double)aLocal);
    }
}

__global__ void finalize_kernel(const double* __restrict__ acc, float* __restrict__ out) {
    const double LN2 = 0.6931471805599453;
    double acc_r = 0.0, acc_a = 0.0;
    for (int s = 0; s < NSLOTS; ++s) { acc_r += acc[s]; acc_a += acc[NSLOTS + s]; }
    double loss = LN2 * (acc_a - (10.0 / 65536.0) * acc_r);
    out[0] = (float)loss;
}

extern "C" void kernel_launch(void* const* d_in, const int* in_sizes, int n_in,
                              void* d_out, int out_size, void* d_ws, size_t ws_size,
                              hipStream_t stream) {
    const float* emb    = (const float*)d_in[0];
    const float* sparse = (const float*)d_in[1];
    const float* deg    = (const float*)d_in[2];
    const int*   heads  = (const int*)d_in[3];
    const int*   tails  = (const int*)d_in[4];
    float* out = (float*)d_out;
    double* ws = (double*)d_ws;

    // zero the accumulator slots without a kernel launch (graph-capture safe)
    hipMemsetAsync(ws, 0, 2 * NSLOTS * sizeof(double), stream);
    hipLaunchKernelGGL(fused_kernel, dim3(NB), dim3(256), 0, stream,
                       emb, deg, sparse, heads, tails, ws);
    hipLaunchKernelGGL(finalize_kernel, dim3(1), dim3(1), 0, stream, ws, out);
}